// Round 1
// 52.379 us; speedup vs baseline: 1.3237x; 1.3237x over previous
//
#include <hip/hip_runtime.h>

typedef __bf16 bf16x8 __attribute__((ext_vector_type(8)));
typedef float  f32x4  __attribute__((ext_vector_type(4)));

#define KDIM    784
#define KSTEP   32
#define NSTEPS  25          // ceil(784/32) -> K padded to 800
#define NCOLS   128
#define NT      8           // 128 / 16 col-tiles
#define WAVES   4
#define ROWS_PER_WAVE 32
#define ROWS_PER_BLOCK (WAVES * ROWS_PER_WAVE)   // 128
#define STAGE_BYTES 16384   // 2 k-steps of B-frags: 2 * 8 frags * 64 lanes * 16 B
#define HSH_PAD 132

// ---------------------------------------------------------------------------
// Prep: Weff[j,k] = sum_{u,v} conv_w[u,v] * fc1_w[j,(r-u)*26+(c-v)], stored as
// bf16 MFMA B-fragments: wfrag[((s*NT + n)*64 + lane)*8 + j] holds
// Weff[col = n*16 + (lane&15)][k = s*32 + (lane>>4)*8 + j]   (0 if k >= 784).
// ---------------------------------------------------------------------------
__global__ __launch_bounds__(256) void prep_weff(
    const float* __restrict__ conv_w,
    const float* __restrict__ fc1_w,
    __bf16* __restrict__ wfrag)
{
  int idx = blockIdx.x * 256 + threadIdx.x;
  if (idx >= NSTEPS * NT * 64) return;
  int lane = idx & 63;
  int n    = (idx >> 6) & (NT - 1);
  int s    = idx >> 9;
  int col  = n * 16 + (lane & 15);
  int kb   = s * KSTEP + (lane >> 4) * 8;
  bf16x8 o;
#pragma unroll
  for (int j = 0; j < 8; ++j) {
    int k = kb + j;
    float v = 0.f;
    if (k < KDIM) {
      int r = k / 28, c = k % 28;
#pragma unroll
      for (int u = 0; u < 3; ++u)
#pragma unroll
        for (int w = 0; w < 3; ++w) {
          int p = r - u, q = c - w;
          if (p >= 0 && p < 26 && q >= 0 && q < 26)
            v = fmaf(conv_w[u * 3 + w], fc1_w[col * 676 + p * 26 + q], v);
        }
    }
    o[j] = (__bf16)v;
  }
  reinterpret_cast<bf16x8*>(wfrag)[idx] = o;
}

__device__ __forceinline__ bf16x8 pack8(f32x4 lo, f32x4 hi) {
  bf16x8 r;
  r[0] = (__bf16)lo[0]; r[1] = (__bf16)lo[1];
  r[2] = (__bf16)lo[2]; r[3] = (__bf16)lo[3];
  r[4] = (__bf16)hi[0]; r[5] = (__bf16)hi[1];
  r[6] = (__bf16)hi[2]; r[7] = (__bf16)hi[3];
  return r;
}

// Split 8 fp32 into bf16 hi + bf16 residual lo (hi+lo reproduces fp32 to ~2^-17)
__device__ __forceinline__ void split8(f32x4 a, f32x4 b, bf16x8& hi, bf16x8& lo) {
#pragma unroll
  for (int j = 0; j < 4; ++j) {
    __bf16 h = (__bf16)a[j]; hi[j] = h; lo[j] = (__bf16)(a[j] - (float)h);
  }
#pragma unroll
  for (int j = 0; j < 4; ++j) {
    __bf16 h = (__bf16)b[j]; hi[4 + j] = h; lo[4 + j] = (__bf16)(b[j] - (float)h);
  }
}

// Async global->LDS copy of one B-frag stage slice. dest is linear
// (wave-uniform base + lane*16) which matches the frag consumption layout.
__device__ __forceinline__ void stage_issue(
    const __bf16* __restrict__ wfrag, unsigned char* dstbuf,
    int stage, int wave, int lane, int nchunks)
{
#pragma unroll
  for (int c = 0; c < 4; ++c) {
    int cw = wave * 4 + c;
    if (cw < nchunks) {
      const unsigned char* src =
          (const unsigned char*)wfrag + (size_t)stage * STAGE_BYTES + cw * 1024 + lane * 16;
      unsigned char* dst = dstbuf + cw * 1024 + lane * 16;
      __builtin_amdgcn_global_load_lds(
          (const __attribute__((address_space(1))) unsigned int*)src,
          (__attribute__((address_space(3))) unsigned int*)dst,
          16, 0, 0);
    }
  }
}

// ---------------------------------------------------------------------------
// Main: per block 4 waves x 32 rows = 128 rows, all 128 h-columns via MFMA.
// B-frags double-buffered in LDS (loaded once per block per stage, not per
// wave). fc2 (128->10) via hi/lo-split bf16 MFMA (fp32-accurate).
// ---------------------------------------------------------------------------
__global__ __launch_bounds__(256, 2) void fused_mlp(
    const float*  __restrict__ x,
    const __bf16* __restrict__ wfrag,
    const float*  __restrict__ fc1_b,
    const float*  __restrict__ fc2_w,
    const float*  __restrict__ fc2_b,
    float*        __restrict__ out)
{
  // 66 KiB: fc1-output h region; first 32 KiB double as the two staging buffers
  // (staging is dead before hsh is first written — barrier-separated).
  __shared__ __align__(16) unsigned char smem[WAVES * ROWS_PER_WAVE * HSH_PAD * 4];
  float (*hsh)[ROWS_PER_WAVE][HSH_PAD] =
      reinterpret_cast<float (*)[ROWS_PER_WAVE][HSH_PAD]>(smem);

  int tid  = threadIdx.x;
  int wave = tid >> 6, lane = tid & 63;
  int lrow = lane & 15;      // A row within 16-tile / B col within 16-tile
  int lgrp = lane >> 4;      // k sub-group
  long wrow0 = (long)blockIdx.x * ROWS_PER_BLOCK + wave * ROWS_PER_WAVE;

  const float* xr0 = x + (wrow0 + lrow) * KDIM;
  const float* xr1 = xr0 + 16 * KDIM;

  f32x4 acc[2][NT];
#pragma unroll
  for (int m = 0; m < 2; ++m)
#pragma unroll
    for (int n = 0; n < NT; ++n) acc[m][n] = (f32x4){0.f, 0.f, 0.f, 0.f};

  // ---- K loop: 12 stages of 2 steps (s=0..23) + tail stage (s=24) ---------
  stage_issue(wfrag, smem, 0, wave, lane, 16);
  int cur = 0;
  for (int t = 0; t < 12; ++t) {
    __syncthreads();   // stage(t) landed (barrier drains vmcnt); prev reads done
    stage_issue(wfrag, smem + (cur ^ 1) * STAGE_BYTES, t + 1, wave, lane,
                (t < 11) ? 16 : 8);

    int k0 = (2 * t) * KSTEP + lgrp * 8;
    f32x4 l00 = *(const f32x4*)(xr0 + k0);
    f32x4 h00 = *(const f32x4*)(xr0 + k0 + 4);
    f32x4 l01 = *(const f32x4*)(xr1 + k0);
    f32x4 h01 = *(const f32x4*)(xr1 + k0 + 4);
    f32x4 l10 = *(const f32x4*)(xr0 + k0 + KSTEP);
    f32x4 h10 = *(const f32x4*)(xr0 + k0 + KSTEP + 4);
    f32x4 l11 = *(const f32x4*)(xr1 + k0 + KSTEP);
    f32x4 h11 = *(const f32x4*)(xr1 + k0 + KSTEP + 4);

    const bf16x8* bp = (const bf16x8*)(smem + cur * STAGE_BYTES) + lane;

    {
      bf16x8 a0 = pack8(l00, h00), a1 = pack8(l01, h01);
      bf16x8 bf[NT];
#pragma unroll
      for (int n = 0; n < NT; ++n) bf[n] = bp[n * 64];
#pragma unroll
      for (int n = 0; n < NT; ++n) {
        acc[0][n] = __builtin_amdgcn_mfma_f32_16x16x32_bf16(a0, bf[n], acc[0][n], 0, 0, 0);
        acc[1][n] = __builtin_amdgcn_mfma_f32_16x16x32_bf16(a1, bf[n], acc[1][n], 0, 0, 0);
      }
    }
    {
      bf16x8 a0 = pack8(l10, h10), a1 = pack8(l11, h11);
      bf16x8 bf[NT];
#pragma unroll
      for (int n = 0; n < NT; ++n) bf[n] = bp[512 + n * 64];
#pragma unroll
      for (int n = 0; n < NT; ++n) {
        acc[0][n] = __builtin_amdgcn_mfma_f32_16x16x32_bf16(a0, bf[n], acc[0][n], 0, 0, 0);
        acc[1][n] = __builtin_amdgcn_mfma_f32_16x16x32_bf16(a1, bf[n], acc[1][n], 0, 0, 0);
      }
    }
    cur ^= 1;
  }

  // ---- tail step s = 24: k in [768, 800), only k < 784 is real ------------
  __syncthreads();   // tail stage landed
  {
    bf16x8 a0, a1;
    if (lgrp < 2) {
      int k = (NSTEPS - 1) * KSTEP + lgrp * 8;   // 768 or 776
      f32x4 lo0 = *(const f32x4*)(xr0 + k);
      f32x4 hi0 = *(const f32x4*)(xr0 + k + 4);
      f32x4 lo1 = *(const f32x4*)(xr1 + k);
      f32x4 hi1 = *(const f32x4*)(xr1 + k + 4);
      a0 = pack8(lo0, hi0);
      a1 = pack8(lo1, hi1);
    } else {
#pragma unroll
      for (int j = 0; j < 8; ++j) { a0[j] = (__bf16)0.f; a1[j] = (__bf16)0.f; }
    }
    const bf16x8* bp = (const bf16x8*)(smem + cur * STAGE_BYTES) + lane;
#pragma unroll
    for (int n = 0; n < NT; ++n) {
      bf16x8 b = bp[n * 64];
      acc[0][n] = __builtin_amdgcn_mfma_f32_16x16x32_bf16(a0, b, acc[0][n], 0, 0, 0);
      acc[1][n] = __builtin_amdgcn_mfma_f32_16x16x32_bf16(a1, b, acc[1][n], 0, 0, 0);
    }
  }
  __syncthreads();   // all staging reads done before hsh overwrites the buffers

  // ---- epilogue: bias + relu -> LDS ---------------------------------------
  // C/D layout (verified m89): col = lane&15, row = (lane>>4)*4 + reg_idx
#pragma unroll
  for (int m = 0; m < 2; ++m)
#pragma unroll
    for (int n = 0; n < NT; ++n) {
      int col = n * 16 + lrow;
      float bias = fc1_b[col];
#pragma unroll
      for (int ri = 0; ri < 4; ++ri) {
        int rl = m * 16 + lgrp * 4 + ri;
        float v = acc[m][n][ri] + bias;
        hsh[wave][rl][col] = fmaxf(v, 0.f);
      }
    }
  __syncthreads();

  // ---- fc2 via MFMA: logits[r,o] = sum_k h[r,k]*w2[o,k], hi/lo split ------
  // B-frag: col(lane&15)=o, k=(lane>>4)*8+j ; built from fc2_w (L2-resident).
  int osafe = (lrow < 10) ? lrow : 9;
  bf16x8 whi[4], wlo[4];
#pragma unroll
  for (int s2 = 0; s2 < 4; ++s2) {
    f32x4 w0 = *(const f32x4*)(fc2_w + osafe * NCOLS + s2 * 32 + lgrp * 8);
    f32x4 w1 = *(const f32x4*)(fc2_w + osafe * NCOLS + s2 * 32 + lgrp * 8 + 4);
    if (lrow >= 10) { w0 = (f32x4){0.f,0.f,0.f,0.f}; w1 = (f32x4){0.f,0.f,0.f,0.f}; }
    split8(w0, w1, whi[s2], wlo[s2]);
  }
  float b2 = (lrow < 10) ? fc2_b[lrow] : 0.f;

#pragma unroll
  for (int m2 = 0; m2 < 2; ++m2) {
    f32x4 acc2 = (f32x4){0.f, 0.f, 0.f, 0.f};
    const float* hr = &hsh[wave][m2 * 16 + lrow][0];
#pragma unroll
    for (int s2 = 0; s2 < 4; ++s2) {
      f32x4 h0 = *(const f32x4*)(hr + s2 * 32 + lgrp * 8);
      f32x4 h1 = *(const f32x4*)(hr + s2 * 32 + lgrp * 8 + 4);
      bf16x8 ahi, alo; split8(h0, h1, ahi, alo);
      acc2 = __builtin_amdgcn_mfma_f32_16x16x32_bf16(ahi, whi[s2], acc2, 0, 0, 0);
      acc2 = __builtin_amdgcn_mfma_f32_16x16x32_bf16(ahi, wlo[s2], acc2, 0, 0, 0);
      acc2 = __builtin_amdgcn_mfma_f32_16x16x32_bf16(alo, whi[s2], acc2, 0, 0, 0);
    }
    // D layout: col(lane&15)=o, row=(lane>>4)*4+reg  -> rows m2*16+lgrp*4+ri
    if (lrow < 10) {
#pragma unroll
      for (int ri = 0; ri < 4; ++ri)
        out[(wrow0 + m2 * 16 + lgrp * 4 + ri) * 10 + lrow] = acc2[ri] + b2;
    }
  }
}

extern "C" void kernel_launch(void* const* d_in, const int* in_sizes, int n_in,
                              void* d_out, int out_size, void* d_ws, size_t ws_size,
                              hipStream_t stream) {
  const float* x      = (const float*)d_in[0];
  const float* conv_w = (const float*)d_in[1];
  const float* fc1_w  = (const float*)d_in[2];
  const float* fc1_b  = (const float*)d_in[3];
  const float* fc2_w  = (const float*)d_in[4];
  const float* fc2_b  = (const float*)d_in[5];
  float* outp = (float*)d_out;
  __bf16* wfrag = (__bf16*)d_ws;                // needs 25*8*64*8*2 B = 200 KiB

  int Btotal = in_sizes[0] / KDIM;              // 65536
  int prep_threads = NSTEPS * NT * 64;          // 12800

  hipLaunchKernelGGL(prep_weff, dim3((prep_threads + 255) / 256), dim3(256), 0, stream,
                     conv_w, fc1_w, wfrag);
  hipLaunchKernelGGL(fused_mlp, dim3(Btotal / ROWS_PER_BLOCK), dim3(256), 0, stream,
                     x, wfrag, fc1_b, fc2_w, fc2_b, outp);
}

// Round 2
// 50.863 us; speedup vs baseline: 1.3632x; 1.0298x over previous
//
#include <hip/hip_runtime.h>

typedef __bf16 bf16x8 __attribute__((ext_vector_type(8)));
typedef float  f32x4  __attribute__((ext_vector_type(4)));

#define KDIM    784
#define KSTEP   32
#define NSTEPS  25          // ceil(784/32) -> K padded to 800
#define NCOLS   128
#define NT      8           // 128 / 16 col-tiles
#define WAVES   4
#define ROWS_PER_WAVE 32
#define ROWS_PER_BLOCK (WAVES * ROWS_PER_WAVE)   // 128
#define STAGE_BYTES 16384   // 2 k-steps of B-frags: 2 * 8 frags * 64 lanes * 16 B
#define HSH_PAD 132
#define HCHUNK  16          // fc2 processes 16 rows per m-chunk (halves LDS)

// ---------------------------------------------------------------------------
// Prep: Weff[j,k] = sum_{u,v} conv_w[u,v] * fc1_w[j,(r-u)*26+(c-v)], stored as
// bf16 MFMA B-fragments: wfrag[((s*NT + n)*64 + lane)*8 + j] holds
// Weff[col = n*16 + (lane&15)][k = s*32 + (lane>>4)*8 + j]   (0 if k >= 784).
// ---------------------------------------------------------------------------
__global__ __launch_bounds__(256) void prep_weff(
    const float* __restrict__ conv_w,
    const float* __restrict__ fc1_w,
    __bf16* __restrict__ wfrag)
{
  int idx = blockIdx.x * 256 + threadIdx.x;
  if (idx >= NSTEPS * NT * 64) return;
  int lane = idx & 63;
  int n    = (idx >> 6) & (NT - 1);
  int s    = idx >> 9;
  int col  = n * 16 + (lane & 15);
  int kb   = s * KSTEP + (lane >> 4) * 8;
  bf16x8 o;
#pragma unroll
  for (int j = 0; j < 8; ++j) {
    int k = kb + j;
    float v = 0.f;
    if (k < KDIM) {
      int r = k / 28, c = k % 28;
#pragma unroll
      for (int u = 0; u < 3; ++u)
#pragma unroll
        for (int w = 0; w < 3; ++w) {
          int p = r - u, q = c - w;
          if (p >= 0 && p < 26 && q >= 0 && q < 26)
            v = fmaf(conv_w[u * 3 + w], fc1_w[col * 676 + p * 26 + q], v);
        }
    }
    o[j] = (__bf16)v;
  }
  reinterpret_cast<bf16x8*>(wfrag)[idx] = o;
}

__device__ __forceinline__ bf16x8 pack8(f32x4 lo, f32x4 hi) {
  bf16x8 r;
  r[0] = (__bf16)lo[0]; r[1] = (__bf16)lo[1];
  r[2] = (__bf16)lo[2]; r[3] = (__bf16)lo[3];
  r[4] = (__bf16)hi[0]; r[5] = (__bf16)hi[1];
  r[6] = (__bf16)hi[2]; r[7] = (__bf16)hi[3];
  return r;
}

// Split 8 fp32 into bf16 hi + bf16 residual lo (hi+lo reproduces fp32 to ~2^-17)
__device__ __forceinline__ void split8(f32x4 a, f32x4 b, bf16x8& hi, bf16x8& lo) {
#pragma unroll
  for (int j = 0; j < 4; ++j) {
    __bf16 h = (__bf16)a[j]; hi[j] = h; lo[j] = (__bf16)(a[j] - (float)h);
  }
#pragma unroll
  for (int j = 0; j < 4; ++j) {
    __bf16 h = (__bf16)b[j]; hi[4 + j] = h; lo[4 + j] = (__bf16)(b[j] - (float)h);
  }
}

// Async global->LDS copy of one B-frag stage slice. dest is linear
// (wave-uniform base + lane*16) which matches the frag consumption layout.
__device__ __forceinline__ void stage_issue(
    const __bf16* __restrict__ wfrag, unsigned char* dstbuf,
    int stage, int wave, int lane, int nchunks)
{
#pragma unroll
  for (int c = 0; c < 4; ++c) {
    int cw = wave * 4 + c;
    if (cw < nchunks) {
      const unsigned char* src =
          (const unsigned char*)wfrag + (size_t)stage * STAGE_BYTES + cw * 1024 + lane * 16;
      unsigned char* dst = dstbuf + cw * 1024 + lane * 16;
      __builtin_amdgcn_global_load_lds(
          (const __attribute__((address_space(1))) unsigned int*)src,
          (__attribute__((address_space(3))) unsigned int*)dst,
          16, 0, 0);
    }
  }
}

// ---------------------------------------------------------------------------
// Main: per block 4 waves x 32 rows = 128 rows, all 128 h-columns via MFMA.
// B-frags double-buffered in LDS; x software-pipelined one stage ahead in
// registers; fc2 (128->10) via hi/lo-split bf16 MFMA in two 16-row chunks
// (hsh only 16 rows/wave -> 34 KB LDS -> 3+ blocks/CU).
// ---------------------------------------------------------------------------
__global__ __launch_bounds__(256, 3) void fused_mlp(
    const float*  __restrict__ x,
    const __bf16* __restrict__ wfrag,
    const float*  __restrict__ fc1_b,
    const float*  __restrict__ fc2_w,
    const float*  __restrict__ fc2_b,
    float*        __restrict__ out)
{
  // 33 KiB: per-wave 16-row fc2 chunk buffers; first 32 KiB double as the two
  // B-frag staging buffers (dead before hsh is first written; barrier-separated).
  __shared__ __align__(16) unsigned char smem[WAVES * HCHUNK * HSH_PAD * 4];
  float (*hsh)[HCHUNK][HSH_PAD] =
      reinterpret_cast<float (*)[HCHUNK][HSH_PAD]>(smem);

  int tid  = threadIdx.x;
  int wave = tid >> 6, lane = tid & 63;
  int lrow = lane & 15;      // A row within 16-tile / B col within 16-tile
  int lgrp = lane >> 4;      // k sub-group
  long wrow0 = (long)blockIdx.x * ROWS_PER_BLOCK + wave * ROWS_PER_WAVE;

  const float* xr0 = x + (wrow0 + lrow) * KDIM;
  const float* xr1 = xr0 + 16 * KDIM;

  f32x4 acc[2][NT];
#pragma unroll
  for (int m = 0; m < 2; ++m)
#pragma unroll
    for (int n = 0; n < NT; ++n) acc[m][n] = (f32x4){0.f, 0.f, 0.f, 0.f};

  // x pipeline registers: one full stage (2 k-steps) ahead
  f32x4 xv[8];
#define LOAD_STAGE(T)                                          \
  {                                                            \
    int k0 = (2 * (T)) * KSTEP + lgrp * 8;                     \
    xv[0] = *(const f32x4*)(xr0 + k0);                         \
    xv[1] = *(const f32x4*)(xr0 + k0 + 4);                     \
    xv[2] = *(const f32x4*)(xr1 + k0);                         \
    xv[3] = *(const f32x4*)(xr1 + k0 + 4);                     \
    xv[4] = *(const f32x4*)(xr0 + k0 + KSTEP);                 \
    xv[5] = *(const f32x4*)(xr0 + k0 + KSTEP + 4);             \
    xv[6] = *(const f32x4*)(xr1 + k0 + KSTEP);                 \
    xv[7] = *(const f32x4*)(xr1 + k0 + KSTEP + 4);             \
  }

  // ---- prologue: stage 0 B-frags + stage 0 x ------------------------------
  stage_issue(wfrag, smem, 0, wave, lane, 16);
  LOAD_STAGE(0);
  int cur = 0;

  // ---- K loop: 12 stages of 2 steps (s=0..23); tail (s=24) after ----------
  for (int t = 0; t < 12; ++t) {
    __syncthreads();   // stage(t) B-frags landed; x(t) regs arrived (vmcnt drain)
    stage_issue(wfrag, smem + (cur ^ 1) * STAGE_BYTES, t + 1, wave, lane,
                (t < 11) ? 16 : 8);

    // pack current-stage A fragments, freeing xv for the next prefetch
    bf16x8 a00 = pack8(xv[0], xv[1]), a01 = pack8(xv[2], xv[3]);
    bf16x8 a10 = pack8(xv[4], xv[5]), a11 = pack8(xv[6], xv[7]);

    // prefetch x for stage t+1 (tail: only k<784 lanes real, rest zero)
    if (t < 11) {
      LOAD_STAGE(t + 1);
    } else {
      if (lgrp < 2) {
        int k = (NSTEPS - 1) * KSTEP + lgrp * 8;   // 768 or 776
        xv[0] = *(const f32x4*)(xr0 + k);
        xv[1] = *(const f32x4*)(xr0 + k + 4);
        xv[2] = *(const f32x4*)(xr1 + k);
        xv[3] = *(const f32x4*)(xr1 + k + 4);
      } else {
        xv[0] = (f32x4){0.f,0.f,0.f,0.f}; xv[1] = (f32x4){0.f,0.f,0.f,0.f};
        xv[2] = (f32x4){0.f,0.f,0.f,0.f}; xv[3] = (f32x4){0.f,0.f,0.f,0.f};
      }
    }

    const bf16x8* bp = (const bf16x8*)(smem + cur * STAGE_BYTES) + lane;
    {
      bf16x8 bf[NT];
#pragma unroll
      for (int n = 0; n < NT; ++n) bf[n] = bp[n * 64];
#pragma unroll
      for (int n = 0; n < NT; ++n) {
        acc[0][n] = __builtin_amdgcn_mfma_f32_16x16x32_bf16(a00, bf[n], acc[0][n], 0, 0, 0);
        acc[1][n] = __builtin_amdgcn_mfma_f32_16x16x32_bf16(a01, bf[n], acc[1][n], 0, 0, 0);
      }
    }
    {
      bf16x8 bf[NT];
#pragma unroll
      for (int n = 0; n < NT; ++n) bf[n] = bp[512 + n * 64];
#pragma unroll
      for (int n = 0; n < NT; ++n) {
        acc[0][n] = __builtin_amdgcn_mfma_f32_16x16x32_bf16(a10, bf[n], acc[0][n], 0, 0, 0);
        acc[1][n] = __builtin_amdgcn_mfma_f32_16x16x32_bf16(a11, bf[n], acc[1][n], 0, 0, 0);
      }
    }
    cur ^= 1;
  }

  // ---- tail step s = 24 (x already in xv[0..3]) ---------------------------
  __syncthreads();   // tail stage landed
  {
    bf16x8 a0 = pack8(xv[0], xv[1]);
    bf16x8 a1 = pack8(xv[2], xv[3]);
    const bf16x8* bp = (const bf16x8*)(smem + cur * STAGE_BYTES) + lane;
#pragma unroll
    for (int n = 0; n < NT; ++n) {
      bf16x8 b = bp[n * 64];
      acc[0][n] = __builtin_amdgcn_mfma_f32_16x16x32_bf16(a0, b, acc[0][n], 0, 0, 0);
      acc[1][n] = __builtin_amdgcn_mfma_f32_16x16x32_bf16(a1, b, acc[1][n], 0, 0, 0);
    }
  }
  __syncthreads();   // all staging reads done before hsh overwrites the buffers

  // ---- fc2 B-fragments from fc2_w (L2-resident), hi/lo split --------------
  // B-frag: col(lane&15)=o, k=(lane>>4)*8+j
  int osafe = (lrow < 10) ? lrow : 9;
  bf16x8 whi[4], wlo[4];
#pragma unroll
  for (int s2 = 0; s2 < 4; ++s2) {
    f32x4 w0 = *(const f32x4*)(fc2_w + osafe * NCOLS + s2 * 32 + lgrp * 8);
    f32x4 w1 = *(const f32x4*)(fc2_w + osafe * NCOLS + s2 * 32 + lgrp * 8 + 4);
    if (lrow >= 10) { w0 = (f32x4){0.f,0.f,0.f,0.f}; w1 = (f32x4){0.f,0.f,0.f,0.f}; }
    split8(w0, w1, whi[s2], wlo[s2]);
  }
  float b2 = (lrow < 10) ? fc2_b[lrow] : 0.f;
  float bcol[NT];
#pragma unroll
  for (int n = 0; n < NT; ++n) bcol[n] = fc1_b[n * 16 + lrow];

  // ---- epilogue in two 16-row chunks: bias+relu -> LDS -> fc2 MFMA --------
  // fc1 C/D layout (m89): col = lane&15, row = (lane>>4)*4 + reg_idx.
  // hsh[wave] is per-wave private: no barriers needed (same-wave LDS is
  // in-order; compiler inserts lgkmcnt waits for the RAW on the same array).
#pragma unroll
  for (int m2 = 0; m2 < 2; ++m2) {
#pragma unroll
    for (int n = 0; n < NT; ++n) {
      int col = n * 16 + lrow;
#pragma unroll
      for (int ri = 0; ri < 4; ++ri) {
        int rl = lgrp * 4 + ri;
        hsh[wave][rl][col] = fmaxf(acc[m2][n][ri] + bcol[n], 0.f);
      }
    }
    f32x4 acc2 = (f32x4){0.f, 0.f, 0.f, 0.f};
    const float* hr = &hsh[wave][lrow][0];
#pragma unroll
    for (int s2 = 0; s2 < 4; ++s2) {
      f32x4 h0 = *(const f32x4*)(hr + s2 * 32 + lgrp * 8);
      f32x4 h1 = *(const f32x4*)(hr + s2 * 32 + lgrp * 8 + 4);
      bf16x8 ahi, alo; split8(h0, h1, ahi, alo);
      acc2 = __builtin_amdgcn_mfma_f32_16x16x32_bf16(ahi, whi[s2], acc2, 0, 0, 0);
      acc2 = __builtin_amdgcn_mfma_f32_16x16x32_bf16(ahi, wlo[s2], acc2, 0, 0, 0);
      acc2 = __builtin_amdgcn_mfma_f32_16x16x32_bf16(alo, whi[s2], acc2, 0, 0, 0);
    }
    // D layout: col(lane&15)=o, row=(lane>>4)*4+reg -> rows m2*16+lgrp*4+ri
    if (lrow < 10) {
#pragma unroll
      for (int ri = 0; ri < 4; ++ri)
        out[(wrow0 + m2 * 16 + lgrp * 4 + ri) * 10 + lrow] = acc2[ri] + b2;
    }
  }
}

extern "C" void kernel_launch(void* const* d_in, const int* in_sizes, int n_in,
                              void* d_out, int out_size, void* d_ws, size_t ws_size,
                              hipStream_t stream) {
  const float* x      = (const float*)d_in[0];
  const float* conv_w = (const float*)d_in[1];
  const float* fc1_w  = (const float*)d_in[2];
  const float* fc1_b  = (const float*)d_in[3];
  const float* fc2_w  = (const float*)d_in[4];
  const float* fc2_b  = (const float*)d_in[5];
  float* outp = (float*)d_out;
  __bf16* wfrag = (__bf16*)d_ws;                // needs 25*8*64*8*2 B = 200 KiB

  int Btotal = in_sizes[0] / KDIM;              // 65536
  int prep_threads = NSTEPS * NT * 64;          // 12800

  hipLaunchKernelGGL(prep_weff, dim3((prep_threads + 255) / 256), dim3(256), 0, stream,
                     conv_w, fc1_w, wfrag);
  hipLaunchKernelGGL(fused_mlp, dim3(Btotal / ROWS_PER_BLOCK), dim3(256), 0, stream,
                     x, wfrag, fc1_b, fc2_w, fc2_b, outp);
}